// Round 10
// baseline (349.864 us; speedup 1.0000x reference)
//
#include <hip/hip_runtime.h>

#define BB 1024
#define TT 512
#define CC 41

__device__ __forceinline__ float rlanef(float xv, int l) {
    return __int_as_float(__builtin_amdgcn_readlane(__float_as_int(xv), l));
}

__global__ __launch_bounds__(64) void crf_viterbi_kernel(
    const float* __restrict__ x,
    const float* __restrict__ start_t,
    const float* __restrict__ end_t,
    const float* __restrict__ trans,
    int* __restrict__ out)   // harness reads out_size int32 elements
{
    __shared__ unsigned char bp_lds[TT * CC];   // rows 0..510 used; 511 = pad
    __shared__ int tags_lds[TT];

    const int lane = threadIdx.x;
    const bool active = lane < CC;
    const int c = active ? lane : (CC - 1);   // clamp for safe loads

    // trans column c in registers (coalesced: lanes contiguous per p)
    float trans_reg[CC];
    #pragma unroll
    for (int p = 0; p < CC; ++p) trans_reg[p] = trans[p * CC + c];

    const float* xb = x + (size_t)blockIdx.x * TT * CC;

    // t = 0: score0 = start_transitions + x[:,0]   (exact ref op order)
    float myscore = start_t[c] + xb[c];

    // 2-deep emit prefetch pipeline
    float emit_cur = xb[1 * CC + c];
    float emit_nxt = xb[2 * CC + c];

    for (int t = 1; t < TT; ++t) {
        const int tf = (t + 2 < TT) ? (t + 2) : (TT - 1);
        const float emit_fut = xb[(size_t)tf * CC + c];

        // Broadcast prev scores via readlane; exact ref op order:
        // (score + trans) + emit. All 41 candidates independent.
        float v[CC];
        #pragma unroll
        for (int p = 0; p < CC; ++p) {
            const float sp = rlanef(myscore, p);
            v[p] = (sp + trans_reg[p]) + emit_cur;
        }

        // Value max: max3-fused tree (pure selection -> bit-exact max).
        float w1[14];
        #pragma unroll
        for (int i = 0; i < 13; ++i)
            w1[i] = fmaxf(fmaxf(v[3 * i], v[3 * i + 1]), v[3 * i + 2]);
        w1[13] = fmaxf(v[39], v[40]);
        float w2[5];
        #pragma unroll
        for (int i = 0; i < 4; ++i)
            w2[i] = fmaxf(fmaxf(w1[3 * i], w1[3 * i + 1]), w1[3 * i + 2]);
        w2[4] = fmaxf(w1[12], w1[13]);
        const float w3a = fmaxf(fmaxf(w2[0], w2[1]), w2[2]);
        const float w3b = fmaxf(w2[3], w2[4]);
        const float m = fmaxf(w3a, w3b);

        // Backpointer: first p with v[p] == m (smallest p on ties ==
        // jnp.argmax first occurrence; m is one of v[p]; no NaNs).
        // 40-deep cndmask chain, OFF the m-recurrence critical path.
        int bp = 40;
        #pragma unroll
        for (int p = 39; p >= 0; --p) bp = (v[p] == m) ? p : bp;

        myscore = m;
        if (active) bp_lds[(t - 1) * CC + lane] = (unsigned char)bp;

        emit_cur = emit_nxt;
        emit_nxt = emit_fut;
    }

    // final = score + end_transitions   (exact ref op order)
    const float fin = myscore + end_t[c];

    // Final argmax over tags (first occurrence), uniform readlane scan.
    float bestv = rlanef(fin, 0);
    int tag = 0;
    #pragma unroll
    for (int i = 1; i < CC; ++i) {
        const float vi = rlanef(fin, i);
        if (vi > bestv) { bestv = vi; tag = i; }
    }

    __syncthreads();   // drain bp_lds writes (single wave: cheap)

    // Pipelined backtrack: row addresses are tag-independent, so batch-load
    // 16 rows (lane c holds bp[r][c]), then resolve with a readlane chain
    // (uniform SGPR index). 32 batch waits instead of 511 dependent loads.
    if (lane == 0) tags_lds[TT - 1] = tag;   // tag at time 511
    for (int g = 31; g >= 0; --g) {
        const int base = g * 16;
        unsigned int rowv[16];
        #pragma unroll
        for (int j = 0; j < 16; ++j)
            rowv[j] = (unsigned int)bp_lds[(base + j) * CC + c];
        #pragma unroll
        for (int j = 15; j >= 0; --j) {
            const int r = base + j;          // row r maps tag@r+1 -> tag@r
            if (r < TT - 1) {
                tag = (int)__builtin_amdgcn_readlane((int)rowv[j], tag);
                if (lane == 0) tags_lds[r] = tag;
            }
        }
    }
    __syncthreads();

    // coalesced output write: one int32 per tag
    int* ob = out + (size_t)blockIdx.x * TT;
    #pragma unroll
    for (int i = 0; i < TT / 64; ++i) ob[lane + 64 * i] = tags_lds[lane + 64 * i];
}

extern "C" void kernel_launch(void* const* d_in, const int* in_sizes, int n_in,
                              void* d_out, int out_size, void* d_ws, size_t ws_size,
                              hipStream_t stream) {
    (void)in_sizes; (void)n_in; (void)d_ws; (void)ws_size; (void)out_size;
    const float* x       = (const float*)d_in[0];
    const float* start_t = (const float*)d_in[1];
    const float* end_t   = (const float*)d_in[2];
    const float* trans   = (const float*)d_in[3];
    int* out = (int*)d_out;

    crf_viterbi_kernel<<<dim3(BB), dim3(64), 0, stream>>>(x, start_t, end_t, trans, out);
}

// Round 11
// 266.819 us; speedup vs baseline: 1.3112x; 1.3112x over previous
//
#include <hip/hip_runtime.h>

#define BB 1024
#define TT 512
#define CC 41

typedef float v2f __attribute__((ext_vector_type(2)));

__device__ __forceinline__ float rlanef(float xv, int l) {
    return __int_as_float(__builtin_amdgcn_readlane(__float_as_int(xv), l));
}

__global__ __launch_bounds__(64) void crf_viterbi_kernel(
    const float* __restrict__ x,
    const float* __restrict__ start_t,
    const float* __restrict__ end_t,
    const float* __restrict__ trans,
    int* __restrict__ out)   // harness reads out_size int32 elements
{
    __shared__ unsigned char bp_lds[TT * CC];   // rows 0..510 used
    __shared__ int tags_lds[TT];

    const int lane = threadIdx.x;
    const bool active = lane < CC;
    const int c = active ? lane : (CC - 1);   // clamp for safe loads

    // trans column c, packed in pairs matching tree level 1
    v2f trans2[20];
    #pragma unroll
    for (int k = 0; k < 20; ++k) {
        trans2[k].x = trans[(2 * k) * CC + c];
        trans2[k].y = trans[(2 * k + 1) * CC + c];
    }
    const float trans40 = trans[40 * CC + c];

    const float* xb = x + (size_t)blockIdx.x * TT * CC;

    // t = 0: score0 = start_transitions + x[:,0]   (exact ref op order)
    float myscore = start_t[c] + xb[c];

    // 2-deep emit prefetch pipeline
    float emit_cur = xb[1 * CC + c];
    float emit_nxt = xb[2 * CC + c];

    #pragma unroll 4
    for (int t = 1; t < TT; ++t) {
        const int tf = (t + 2 < TT) ? (t + 2) : (TT - 1);
        const float emit_fut = xb[(size_t)tf * CC + c];

        // Candidates in packed pairs: (score + trans) + emit, exact ref op
        // order; v_pk_add_f32 opportunity (2 adds/inst), values bit-identical.
        const v2f e2 = {emit_cur, emit_cur};
        float v[CC];
        int  ix[CC];
        #pragma unroll
        for (int k = 0; k < 20; ++k) {
            v2f sp2;
            sp2.x = rlanef(myscore, 2 * k);
            sp2.y = rlanef(myscore, 2 * k + 1);
            const v2f cand = (sp2 + trans2[k]) + e2;
            v[2 * k]     = cand.x;  ix[2 * k]     = 2 * k;
            v[2 * k + 1] = cand.y;  ix[2 * k + 1] = 2 * k + 1;
        }
        v[40] = (rlanef(myscore, 40) + trans40) + emit_cur;
        ix[40] = 40;

        // Segment-tree argmax over contiguous blocks (depth 6): keep-left on
        // strict > == jnp.argmax first-occurrence.
#define COMBINE(i, j) do { \
            if (v[(j)] > v[(i)]) { v[(i)] = v[(j)]; ix[(i)] = ix[(j)]; } \
        } while (0)
        #pragma unroll
        for (int i = 0; i < 20; ++i) COMBINE(2 * i, 2 * i + 1);   // [2i,2i+1]
        #pragma unroll
        for (int i = 0; i < 10; ++i) COMBINE(4 * i, 4 * i + 2);   // [4i..4i+3]
        #pragma unroll
        for (int i = 0; i < 5; ++i)  COMBINE(8 * i, 8 * i + 4);   // [8i..8i+7]
        COMBINE(0, 8);    // [0..15]
        COMBINE(16, 24);  // [16..31]
        COMBINE(0, 16);   // [0..31]
        COMBINE(32, 40);  // [32..40]
        COMBINE(0, 32);   // [0..40]
#undef COMBINE

        myscore = v[0];
        if (active) bp_lds[(t - 1) * CC + lane] = (unsigned char)ix[0];

        emit_cur = emit_nxt;
        emit_nxt = emit_fut;
    }

    // final = score + end_transitions   (exact ref op order)
    const float fin = myscore + end_t[c];

    // Final argmax over tags (first occurrence), uniform readlane scan.
    float bestv = rlanef(fin, 0);
    int tag = 0;
    #pragma unroll
    for (int i = 1; i < CC; ++i) {
        const float vi = rlanef(fin, i);
        if (vi > bestv) { bestv = vi; tag = i; }
    }

    __syncthreads();   // drain bp_lds writes (single wave: cheap)

    // Pipelined backtrack (proven in R10): batch-load 16 rows (lane c holds
    // bp[r][c]) then resolve via readlane chain (uniform index). 32 batch
    // waits instead of 511 dependent loads.
    if (lane == 0) tags_lds[TT - 1] = tag;   // tag at time 511
    for (int g = 31; g >= 0; --g) {
        const int base = g * 16;
        unsigned int rowv[16];
        #pragma unroll
        for (int j = 0; j < 16; ++j)
            rowv[j] = (unsigned int)bp_lds[(base + j) * CC + c];
        #pragma unroll
        for (int j = 15; j >= 0; --j) {
            const int r = base + j;          // row r maps tag@r+1 -> tag@r
            if (r < TT - 1) {
                tag = (int)__builtin_amdgcn_readlane((int)rowv[j], tag);
                if (lane == 0) tags_lds[r] = tag;
            }
        }
    }
    __syncthreads();

    // coalesced output write: one int32 per tag
    int* ob = out + (size_t)blockIdx.x * TT;
    #pragma unroll
    for (int i = 0; i < TT / 64; ++i) ob[lane + 64 * i] = tags_lds[lane + 64 * i];
}

extern "C" void kernel_launch(void* const* d_in, const int* in_sizes, int n_in,
                              void* d_out, int out_size, void* d_ws, size_t ws_size,
                              hipStream_t stream) {
    (void)in_sizes; (void)n_in; (void)d_ws; (void)ws_size; (void)out_size;
    const float* x       = (const float*)d_in[0];
    const float* start_t = (const float*)d_in[1];
    const float* end_t   = (const float*)d_in[2];
    const float* trans   = (const float*)d_in[3];
    int* out = (int*)d_out;

    crf_viterbi_kernel<<<dim3(BB), dim3(64), 0, stream>>>(x, start_t, end_t, trans, out);
}

// Round 12
// 266.361 us; speedup vs baseline: 1.3135x; 1.0017x over previous
//
#include <hip/hip_runtime.h>

#define BB 1024
#define TT 512
#define CC 41
#define BPS 64   // bp_lds row stride: 64 -> unconditional 64-lane writes, no exec-mask flips

__device__ __forceinline__ float rlanef(float xv, int l) {
    return __int_as_float(__builtin_amdgcn_readlane(__float_as_int(xv), l));
}

__global__ __launch_bounds__(64) void crf_viterbi_kernel(
    const float* __restrict__ x,
    const float* __restrict__ start_t,
    const float* __restrict__ end_t,
    const float* __restrict__ trans,
    int* __restrict__ out)   // harness reads out_size int32 elements
{
    __shared__ unsigned char bp_lds[(TT - 1) * BPS];   // rows 0..510, cols 41..63 = pad
    __shared__ int tags_lds[TT];

    const int lane = threadIdx.x;
    const int c = (lane < CC) ? lane : (CC - 1);   // clamp for safe loads

    // trans column c in registers (coalesced: lanes contiguous per p)
    float trans_reg[CC];
    #pragma unroll
    for (int p = 0; p < CC; ++p) trans_reg[p] = trans[p * CC + c];

    const float* xb = x + (size_t)blockIdx.x * TT * CC;

    // t = 0: score0 = start_transitions + x[:,0]   (exact ref op order)
    float myscore = start_t[c] + xb[c];

    // 2-deep emit prefetch pipeline
    float emit_cur = xb[1 * CC + c];
    float emit_nxt = xb[2 * CC + c];

    for (int t = 1; t < TT; ++t) {
        const int tf = (t + 2 < TT) ? (t + 2) : (TT - 1);   // uniform -> SALU
        const float emit_fut = xb[(size_t)tf * CC + c];

        // Batch all 41 broadcasts first (wave-uniform -> SGPRs). Separating
        // them from the dependent adds hides the VALU->SGPR->VALU hazard and
        // gives the scheduler a 41-wide independent issue window.
        float sp[CC];
        #pragma unroll
        for (int p = 0; p < CC; ++p) sp[p] = rlanef(myscore, p);

        // Candidates: exact ref op order (score + trans) + emit.
        float v[CC];
        int  ix[CC];
        #pragma unroll
        for (int p = 0; p < CC; ++p) {
            v[p]  = (sp[p] + trans_reg[p]) + emit_cur;
            ix[p] = p;
        }

        // Segment-tree argmax over contiguous blocks (depth 6): keep-left on
        // strict > == jnp.argmax first-occurrence.
#define COMBINE(i, j) do { \
            if (v[(j)] > v[(i)]) { v[(i)] = v[(j)]; ix[(i)] = ix[(j)]; } \
        } while (0)
        #pragma unroll
        for (int i = 0; i < 20; ++i) COMBINE(2 * i, 2 * i + 1);   // [2i,2i+1]
        #pragma unroll
        for (int i = 0; i < 10; ++i) COMBINE(4 * i, 4 * i + 2);   // [4i..4i+3]
        #pragma unroll
        for (int i = 0; i < 5; ++i)  COMBINE(8 * i, 8 * i + 4);   // [8i..8i+7]
        COMBINE(0, 8);    // [0..15]
        COMBINE(16, 24);  // [16..31]
        COMBINE(0, 16);   // [0..31]
        COMBINE(32, 40);  // [32..40]
        COMBINE(0, 32);   // [0..40]
#undef COMBINE

        myscore = v[0];
        // Unconditional store: lanes 41-63 write pad columns (never read).
        bp_lds[(t - 1) * BPS + lane] = (unsigned char)ix[0];

        emit_cur = emit_nxt;
        emit_nxt = emit_fut;
    }

    // final = score + end_transitions   (exact ref op order)
    const float fin = myscore + end_t[c];

    // Final argmax over tags (first occurrence), uniform readlane scan.
    float bestv = rlanef(fin, 0);
    int tag = 0;
    #pragma unroll
    for (int i = 1; i < CC; ++i) {
        const float vi = rlanef(fin, i);
        if (vi > bestv) { bestv = vi; tag = i; }
    }

    __syncthreads();   // drain bp_lds writes (single wave: cheap)

    // Pipelined backtrack (proven R10/R11): batch-load 16 rows (lane c holds
    // bp[r][lane]) then resolve via readlane chain (uniform index). 32 batch
    // waits instead of 511 dependent loads.
    if (lane == 0) tags_lds[TT - 1] = tag;   // tag at time 511
    for (int g = 31; g >= 0; --g) {
        const int base = g * 16;
        unsigned int rowv[16];
        #pragma unroll
        for (int j = 0; j < 16; ++j)
            rowv[j] = (unsigned int)bp_lds[(base + j) * BPS + lane];
        #pragma unroll
        for (int j = 15; j >= 0; --j) {
            const int r = base + j;          // row r maps tag@r+1 -> tag@r
            if (r < TT - 1) {
                tag = (int)__builtin_amdgcn_readlane((int)rowv[j], tag);
                if (lane == 0) tags_lds[r] = tag;
            }
        }
    }
    __syncthreads();

    // coalesced output write: one int32 per tag
    int* ob = out + (size_t)blockIdx.x * TT;
    #pragma unroll
    for (int i = 0; i < TT / 64; ++i) ob[lane + 64 * i] = tags_lds[lane + 64 * i];
}

extern "C" void kernel_launch(void* const* d_in, const int* in_sizes, int n_in,
                              void* d_out, int out_size, void* d_ws, size_t ws_size,
                              hipStream_t stream) {
    (void)in_sizes; (void)n_in; (void)d_ws; (void)ws_size; (void)out_size;
    const float* x       = (const float*)d_in[0];
    const float* start_t = (const float*)d_in[1];
    const float* end_t   = (const float*)d_in[2];
    const float* trans   = (const float*)d_in[3];
    int* out = (int*)d_out;

    crf_viterbi_kernel<<<dim3(BB), dim3(64), 0, stream>>>(x, start_t, end_t, trans, out);
}